// Round 6
// baseline (236.585 us; speedup 1.0000x reference)
//
#include <hip/hip_runtime.h>

typedef __bf16 bf16x8 __attribute__((ext_vector_type(8)));
typedef __bf16 bf16x4 __attribute__((ext_vector_type(4)));
typedef _Float16 f16x4v __attribute__((ext_vector_type(4)));
typedef float f32x4 __attribute__((ext_vector_type(4)));
typedef float f32x16 __attribute__((ext_vector_type(16)));
typedef unsigned short u16;
typedef unsigned int u32;

constexpr int Bc = 4, Sc = 2048, Dc = 1024, Hc = 16, DHc = 64;
constexpr int Mrows = Bc * Sc;  // 8192
constexpr size_t MK = (size_t)Mrows * Dc;
constexpr size_t WK = (size_t)Dc * Dc;

__device__ __forceinline__ u16 f2bf(float f) {
  u32 u = __float_as_uint(f);
  u = (u + 0x7fffu + ((u >> 16) & 1u)) >> 16;  // RTNE
  return (u16)u;
}

#define LDSP(p) ((__attribute__((address_space(3))) void*)(p))
#define GLBP(p) ((const __attribute__((address_space(1))) void*)(p))

// ---------------- fp32 -> bf16 conversion (fused via blockIdx.y) ----------------
__global__ __launch_bounds__(256) void cvt3_kernel(const float* __restrict__ a,
                                                   const float* __restrict__ b,
                                                   const float* __restrict__ c,
                                                   ushort4* __restrict__ out, int n4) {
  const float4* in = (const float4*)(blockIdx.y == 0 ? a : blockIdx.y == 1 ? b : c);
  ushort4* o = out + (size_t)blockIdx.y * n4;
  int stride = gridDim.x * blockDim.x;
  for (int i = blockIdx.x * blockDim.x + threadIdx.x; i < n4; i += stride) {
    float4 v = in[i];
    ushort4 r;
    r.x = f2bf(v.x); r.y = f2bf(v.y); r.z = f2bf(v.z); r.w = f2bf(v.w);
    o[i] = r;
  }
}

__global__ __launch_bounds__(256) void cvt4_kernel(const float* __restrict__ a,
                                                   const float* __restrict__ b,
                                                   const float* __restrict__ c,
                                                   const float* __restrict__ d,
                                                   ushort4* __restrict__ out, int n4) {
  const float4* in = (const float4*)(blockIdx.y == 0 ? a : blockIdx.y == 1 ? b
                                     : blockIdx.y == 2 ? c : d);
  ushort4* o = out + (size_t)blockIdx.y * n4;
  int stride = gridDim.x * blockDim.x;
  for (int i = blockIdx.x * blockDim.x + threadIdx.x; i < n4; i += stride) {
    float4 v = in[i];
    ushort4 r;
    r.x = f2bf(v.x); r.y = f2bf(v.y); r.z = f2bf(v.z); r.w = f2bf(v.w);
    o[i] = r;
  }
}

// ---------------- GEMM v4: 2-phase/K-tile, 8-MFMA clusters ----------------
// C[m,n] = sum_k A[m,k]*Bt[n,k] + bias[n].  BM=256, BN=128, BK=64, 512 thr
// (8 waves = 4M x 2N, wave out 64x64 via mfma_32x32x16_bf16).  Ring-3 LDS,
// 6 global_load_lds/wave/K-tile split 3+3 over 2 phases, counted vmcnt(6)
// once per K-tile, 3 raw s_barriers per K-tile.  16B-granule XOR swizzle
// (g ^= row&7) staged via pre-swizzled global source (rule 21).
enum GemmMode { MODE_Q = 0, MODE_K = 1, MODE_V = 2, MODE_OUT = 3 };

template <int FUSED3>
__global__ __launch_bounds__(512, 2) void gemm8(const u16* __restrict__ A0,
                                                const u16* __restrict__ Bt0,
                                                const float* __restrict__ b0,
                                                const float* __restrict__ b1,
                                                const float* __restrict__ b2,
                                                void* __restrict__ out0) {
  constexpr int K = 1024, NT = 16;
  __shared__ u16 lds[3 * 24576];  // 3 x (A 256x64 | B 128x64)

  const int y = FUSED3 ? (int)blockIdx.y : 3;
  const u16* A = A0 + (FUSED3 ? (size_t)blockIdx.y * MK : 0);
  const u16* Bt = Bt0 + (FUSED3 ? (size_t)blockIdx.y * WK : 0);
  const float* bias = FUSED3 ? (y == 0 ? b0 : y == 1 ? b1 : b2) : b0;

  // bijective XCD swizzle: 256 blocks, 8 XCDs
  const int wg = (blockIdx.x & 7) * 32 + (blockIdx.x >> 3);
  const int tm = wg >> 3, tn = wg & 7;
  const int row0 = tm << 8, col0 = tn << 7;

  const int t_ = threadIdx.x, w = t_ >> 6, l = t_ & 63;
  const int wm = w >> 1, wn = w & 1;
  const int col = l & 31, hh = l >> 5;

  f32x16 acc[2][2] = {};

  auto stA = [&](int tile, int i) {
    u16* buf = &lds[(tile % 3) * 24576];
    const int c = (w * 4 + i) * 64 + l;
    const int r = c >> 3, gl = c & 7;
    __builtin_amdgcn_global_load_lds(
        GLBP(A + (size_t)(row0 + r) * K + (tile << 6) + ((gl ^ (r & 7)) << 3)),
        LDSP(buf + (w * 4 + i) * 512), 16, 0, 0);
  };
  auto stB = [&](int tile, int i) {
    u16* buf = &lds[(tile % 3) * 24576] + 16384;
    const int c = (w * 2 + i) * 64 + l;
    const int r = c >> 3, gl = c & 7;
    __builtin_amdgcn_global_load_lds(
        GLBP(Bt + (size_t)(col0 + r) * K + (tile << 6) + ((gl ^ (r & 7)) << 3)),
        LDSP(buf + (w * 2 + i) * 512), 16, 0, 0);
  };

  // prologue: stage tiles 0 and 1; wait tile 0 (6 newest outstanding allowed)
#pragma unroll
  for (int i = 0; i < 4; ++i) stA(0, i);
#pragma unroll
  for (int i = 0; i < 2; ++i) stB(0, i);
#pragma unroll
  for (int i = 0; i < 4; ++i) stA(1, i);
#pragma unroll
  for (int i = 0; i < 2; ++i) stB(1, i);
  asm volatile("s_waitcnt vmcnt(6)" ::: "memory");
  __builtin_amdgcn_s_barrier();

  const int ar0 = wm * 64 + col, ar1 = ar0 + 32;
  const int br0 = wn * 64 + col, br1 = br0 + 32;

#pragma unroll 1
  for (int t = 0; t < NT; ++t) {
    const u16* abuf = &lds[(t % 3) * 24576];
    const u16* bbuf = abuf + 16384;
#pragma unroll
    for (int ph = 0; ph < 2; ++ph) {
      bf16x8 a0[2], a1[2], q0[2], q1[2];
#pragma unroll
      for (int k2 = 0; k2 < 2; ++k2) {
        const int ks = ph * 2 + k2;
        a0[k2] = *(const bf16x8*)&abuf[ar0 * 64 + ((((ks << 1) + hh) ^ (ar0 & 7)) << 3)];
        a1[k2] = *(const bf16x8*)&abuf[ar1 * 64 + ((((ks << 1) + hh) ^ (ar1 & 7)) << 3)];
        q0[k2] = *(const bf16x8*)&bbuf[br0 * 64 + ((((ks << 1) + hh) ^ (br0 & 7)) << 3)];
        q1[k2] = *(const bf16x8*)&bbuf[br1 * 64 + ((((ks << 1) + hh) ^ (br1 & 7)) << 3)];
      }
      if (t + 2 < NT) {
        if (ph == 0) { stA(t + 2, 0); stA(t + 2, 1); stA(t + 2, 2); }
        else         { stA(t + 2, 3); stB(t + 2, 0); stB(t + 2, 1); }
      }
      __builtin_amdgcn_sched_barrier(0);
      __builtin_amdgcn_s_barrier();
      __builtin_amdgcn_sched_barrier(0);
      __builtin_amdgcn_s_setprio(1);
#pragma unroll
      for (int k2 = 0; k2 < 2; ++k2) {
        acc[0][0] = __builtin_amdgcn_mfma_f32_32x32x16_bf16(a0[k2], q0[k2], acc[0][0], 0, 0, 0);
        acc[0][1] = __builtin_amdgcn_mfma_f32_32x32x16_bf16(a0[k2], q1[k2], acc[0][1], 0, 0, 0);
        acc[1][0] = __builtin_amdgcn_mfma_f32_32x32x16_bf16(a1[k2], q0[k2], acc[1][0], 0, 0, 0);
        acc[1][1] = __builtin_amdgcn_mfma_f32_32x32x16_bf16(a1[k2], q1[k2], acc[1][1], 0, 0, 0);
      }
      __builtin_amdgcn_s_setprio(0);
      __builtin_amdgcn_sched_barrier(0);
    }
    if (t + 2 < NT)      asm volatile("s_waitcnt vmcnt(6)" ::: "memory");
    else if (t + 1 < NT) asm volatile("s_waitcnt vmcnt(0)" ::: "memory");
    __builtin_amdgcn_s_barrier();
  }

  // epilogue: C/D 32x32 layout: col = lane&31, row = (r&3) + 8*(r>>2) + 4*(lane>>5)
#pragma unroll
  for (int mi = 0; mi < 2; ++mi)
#pragma unroll
    for (int ni = 0; ni < 2; ++ni) {
      const int n = col0 + wn * 64 + ni * 32 + col;
      const float bv = bias[n];
      const int mbase = row0 + wm * 64 + mi * 32 + 4 * hh;
      if (y == 3) {  // out-proj: fp32
        float* O = (float*)out0;
#pragma unroll
        for (int r = 0; r < 16; ++r) {
          const int m = mbase + (r & 3) + 8 * (r >> 2);
          O[(size_t)m * Dc + n] = acc[mi][ni][r] + bv;
        }
      } else if (y == 2) {  // V: transposed + f16, Vt[((b*H+h)*DH+dh)*S + s]
        u16* Vt = (u16*)out0 + 2 * MK;
        const int h = n >> 6, dh = n & 63;
#pragma unroll
        for (int qg = 0; qg < 4; ++qg) {
          const int s0 = mbase + 8 * qg;
          const int b = s0 >> 11, s = s0 & (Sc - 1);
          f16x4v pk;
#pragma unroll
          for (int r4 = 0; r4 < 4; ++r4) pk[r4] = (_Float16)(acc[mi][ni][qg * 4 + r4] + bv);
          *(f16x4v*)&Vt[((size_t)((b * Hc + h) * DHc + dh)) * Sc + s] = pk;
        }
      } else {  // Q or K: head-split bf16, Q scaled by 1/8 * log2(e)
        u16* Oh = (u16*)out0 + (size_t)y * MK;
        const float scl = (y == 0) ? 0.125f * 1.44269504089f : 1.f;
        const int h = n >> 6, dh = n & 63;
#pragma unroll
        for (int r = 0; r < 16; ++r) {
          const int m = mbase + (r & 3) + 8 * (r >> 2);
          const int b = m >> 11, s = m & (Sc - 1);
          Oh[((size_t)((b * Hc + h) * Sc + s)) * DHc + dh] = f2bf((acc[mi][ni][r] + bv) * scl);
        }
      }
    }
}

// ---------------- Flash attention v3: KV macrotile 128, in-register softmax --------
// 4 waves/block, 32 q-rows/wave.  Staging+barriers per 128 kv rows (K 16KB XOR
// row&7; V^T 64x128 f16 16KB XOR row&15 in 16B granules); compute = 2x 64-row
// passes (register pressure unchanged).  QK: mfma_32x32x16_bf16 (S^T), PV:
// mfma_32x32x8f16, P stays in registers.
__global__ __launch_bounds__(256, 2) void attn3_kernel(const u16* __restrict__ Qh,
                                                       const u16* __restrict__ Kh,
                                                       const u16* __restrict__ Vt,
                                                       u16* __restrict__ ctx) {
  __shared__ u16 smem[16384];  // 32 KB: K[128][64] bf16 | V^T[64][128] f16
  u16* K_lds = smem;
  u16* V_lds = smem + 8192;

  const int wid = (blockIdx.x & 7) * 128 + (blockIdx.x >> 3);  // XCD swizzle
  const int qt = wid & 15, bh = wid >> 4;
  const int t = threadIdx.x, w = t >> 6, l = t & 63;
  const int q = l & 31, h = l >> 5;
  const int q0 = qt * 128 + w * 32;

  bf16x8 qf[4];
  {
    const u16* qp = Qh + ((size_t)bh * Sc + q0 + q) * DHc + h * 8;
#pragma unroll
    for (int kk = 0; kk < 4; ++kk) qf[kk] = *(const bf16x8*)(qp + kk * 16);
  }

  f32x16 oacc[2] = {};
  float m_run = -3.0e38f, l_run = 0.f;

  for (int kt = 0; kt < Sc; kt += 128) {
    __syncthreads();
    // K: 16 chunks of 1KB (8 rows x 128B); wave w -> chunks w*4+c
#pragma unroll
    for (int c = 0; c < 4; ++c) {
      const int kb = (w * 4 + c) * 8;
      const int row = kb + (l >> 3);
      const int sg = (l & 7) ^ (row & 7);
      __builtin_amdgcn_global_load_lds(GLBP(Kh + ((size_t)bh * Sc + kt + row) * DHc + sg * 8),
                                       LDSP(&K_lds[kb * 64]), 16, 0, 0);
    }
    // V^T: 16 chunks of 1KB (4 rows x 256B)
#pragma unroll
    for (int c = 0; c < 4; ++c) {
      const int vb = (w * 4 + c) * 4;
      const int row = vb + (l >> 4);
      const int sg = (l & 15) ^ (row & 15);
      __builtin_amdgcn_global_load_lds(GLBP(Vt + ((size_t)bh * DHc + row) * Sc + kt + sg * 8),
                                       LDSP(&V_lds[vb * 128]), 16, 0, 0);
    }
    __syncthreads();

#pragma unroll
    for (int h64 = 0; h64 < 2; ++h64) {
      // S^T[k][q] = K · Q^T
      f32x16 sacc[2];
#pragma unroll
      for (int kt32 = 0; kt32 < 2; ++kt32) {
        f32x16 s_ = {};
        const int krow = h64 * 64 + kt32 * 32 + q;
        __builtin_amdgcn_s_setprio(1);
#pragma unroll
        for (int kk = 0; kk < 4; ++kk) {
          bf16x8 kf = *(const bf16x8*)&K_lds[krow * 64 + ((2 * kk + h) ^ (krow & 7)) * 8];
          s_ = __builtin_amdgcn_mfma_f32_32x32x16_bf16(kf, qf[kk], s_, 0, 0, 0);
        }
        __builtin_amdgcn_s_setprio(0);
        sacc[kt32] = s_;
      }

      // online softmax (log2 domain), defer-max (THR=8)
      float mx = sacc[0][0];
#pragma unroll
      for (int r = 1; r < 16; ++r) mx = fmaxf(mx, sacc[0][r]);
#pragma unroll
      for (int r = 0; r < 16; ++r) mx = fmaxf(mx, sacc[1][r]);
      mx = fmaxf(mx, __shfl_xor(mx, 32));
      if (__any(mx - m_run > 8.f)) {
        const float mnew = fmaxf(m_run, mx);
        const float corr = __builtin_amdgcn_exp2f(m_run - mnew);
        m_run = mnew;
        l_run *= corr;
#pragma unroll
        for (int dt = 0; dt < 2; ++dt)
#pragma unroll
          for (int r = 0; r < 16; ++r) oacc[dt][r] *= corr;
      }
      float sum = 0.f;
      f16x4v pa[2][4];  // k = kt32*32 + kc*8 + 4h + j
#pragma unroll
      for (int kt32 = 0; kt32 < 2; ++kt32)
#pragma unroll
        for (int kc = 0; kc < 4; ++kc)
#pragma unroll
          for (int j = 0; j < 4; ++j) {
            float pv = __builtin_amdgcn_exp2f(sacc[kt32][kc * 4 + j] - m_run);
            sum += pv;
            pa[kt32][kc][j] = (_Float16)pv;
          }
      sum += __shfl_xor(sum, 32);
      l_run += sum;

      // O^T += V^T · P
      __builtin_amdgcn_s_setprio(1);
#pragma unroll
      for (int kt32 = 0; kt32 < 2; ++kt32)
#pragma unroll
        for (int kc = 0; kc < 4; ++kc)
#pragma unroll
          for (int dt = 0; dt < 2; ++dt) {
            const int vrow = dt * 32 + q;
            const int kslot = h64 * 8 + kt32 * 4 + kc;
            f16x4v vf = *(const f16x4v*)&V_lds[vrow * 128 + ((kslot ^ (vrow & 15)) * 8) + 4 * h];
            oacc[dt] = __builtin_amdgcn_mfma_f32_32x32x8f16(vf, pa[kt32][kc], oacc[dt], 0, 0, 0);
          }
      __builtin_amdgcn_s_setprio(0);
    }
  }

  // epilogue: normalize, transpose O^T -> O through LDS, coalesced ctx write
  __syncthreads();
  const float inv = 1.f / l_run;
  u16* E = smem + w * 2048;
#pragma unroll
  for (int dt = 0; dt < 2; ++dt)
#pragma unroll
    for (int rg = 0; rg < 4; ++rg) {
      bf16x4 pk;
#pragma unroll
      for (int j = 0; j < 4; ++j) pk[j] = (__bf16)(oacc[dt][rg * 4 + j] * inv);
      const int dh0 = dt * 32 + rg * 8 + 4 * h;
      int byte = q * 128 + dh0 * 2;
      byte ^= (q & 7) << 4;
      *(bf16x4*)((char*)E + byte) = pk;
    }
  __syncthreads();
  const int b = bh >> 4, head = bh & 15;
  const size_t crow = ((size_t)(b * Sc + q0 + q)) * Dc + head * 64 + h * 32;
#pragma unroll
  for (int i = 0; i < 4; ++i) {
    const int g = (4 * h + i) ^ (q & 7);
    uint4 tv = *(const uint4*)((char*)E + q * 128 + g * 16);
    *(uint4*)((u16*)ctx + crow + i * 8) = tv;
  }
}

// ---------------- launcher ----------------
extern "C" void kernel_launch(void* const* d_in, const int* in_sizes, int n_in,
                              void* d_out, int out_size, void* d_ws, size_t ws_size,
                              hipStream_t stream) {
  const float* q  = (const float*)d_in[0];
  const float* k  = (const float*)d_in[1];
  const float* v  = (const float*)d_in[2];
  const float* Wq = (const float*)d_in[3];
  const float* bq = (const float*)d_in[4];
  const float* Wk = (const float*)d_in[5];
  const float* bk = (const float*)d_in[6];
  const float* Wv = (const float*)d_in[7];
  const float* bv = (const float*)d_in[8];
  const float* Wo = (const float*)d_in[9];
  const float* bo = (const float*)d_in[10];
  float* out = (float*)d_out;

  u16* qb  = (u16*)d_ws;          // qb,kb,vb contiguous (3*MK)
  u16* Wqb = qb + 3 * MK;         // Wq,Wk,Wv,Wo contiguous (4*WK)
  u16* Qh  = Wqb + 4 * WK;        // Qh,Kh,Vt contiguous (3*MK)
  u16* Kh  = Qh + MK;
  u16* VtB = Kh + MK;
  u16* ctx = VtB + MK;

  cvt3_kernel<<<dim3(2048, 3), 256, 0, stream>>>(q, k, v, (ushort4*)qb, (int)(MK / 4));
  cvt4_kernel<<<dim3(512, 4), 256, 0, stream>>>(Wq, Wk, Wv, Wo, (ushort4*)Wqb, (int)(WK / 4));

  gemm8<1><<<dim3(256, 3), 512, 0, stream>>>(qb, Wqb, bq, bk, bv, (void*)Qh);

  attn3_kernel<<<1024, 256, 0, stream>>>(Qh, Kh, VtB, ctx);

  gemm8<0><<<dim3(256, 1), 512, 0, stream>>>(ctx, Wqb + 3 * WK, bo, bo, bo, (void*)out);
}

// Round 7
// 220.480 us; speedup vs baseline: 1.0730x; 1.0730x over previous
//
#include <hip/hip_runtime.h>

typedef __bf16 bf16x8 __attribute__((ext_vector_type(8)));
typedef __bf16 bf16x4 __attribute__((ext_vector_type(4)));
typedef _Float16 f16x8 __attribute__((ext_vector_type(8)));
typedef _Float16 f16x4v __attribute__((ext_vector_type(4)));
typedef float f32x4 __attribute__((ext_vector_type(4)));
typedef float f32x16 __attribute__((ext_vector_type(16)));
typedef unsigned short u16;
typedef unsigned int u32;
typedef unsigned int u32x4 __attribute__((ext_vector_type(4)));

constexpr int Bc = 4, Sc = 2048, Dc = 1024, Hc = 16, DHc = 64;
constexpr int Mrows = Bc * Sc;  // 8192
constexpr size_t MK = (size_t)Mrows * Dc;
constexpr size_t WK = (size_t)Dc * Dc;

__device__ __forceinline__ u16 f2bf(float f) {
  u32 u = __float_as_uint(f);
  u = (u + 0x7fffu + ((u >> 16) & 1u)) >> 16;  // RTNE
  return (u16)u;
}

#define LDSP(p) ((__attribute__((address_space(3))) void*)(p))
#define GLBP(p) ((const __attribute__((address_space(1))) void*)(p))

// ---------------- fp32 -> bf16 conversion (fused via blockIdx.y) ----------------
__global__ __launch_bounds__(256) void cvt3_kernel(const float* __restrict__ a,
                                                   const float* __restrict__ b,
                                                   const float* __restrict__ c,
                                                   ushort4* __restrict__ out, int n4) {
  const float4* in = (const float4*)(blockIdx.y == 0 ? a : blockIdx.y == 1 ? b : c);
  ushort4* o = out + (size_t)blockIdx.y * n4;
  int stride = gridDim.x * blockDim.x;
  for (int i = blockIdx.x * blockDim.x + threadIdx.x; i < n4; i += stride) {
    float4 v = in[i];
    ushort4 r;
    r.x = f2bf(v.x); r.y = f2bf(v.y); r.z = f2bf(v.z); r.w = f2bf(v.w);
    o[i] = r;
  }
}

__global__ __launch_bounds__(256) void cvt4_kernel(const float* __restrict__ a,
                                                   const float* __restrict__ b,
                                                   const float* __restrict__ c,
                                                   const float* __restrict__ d,
                                                   ushort4* __restrict__ out, int n4) {
  const float4* in = (const float4*)(blockIdx.y == 0 ? a : blockIdx.y == 1 ? b
                                     : blockIdx.y == 2 ? c : d);
  ushort4* o = out + (size_t)blockIdx.y * n4;
  int stride = gridDim.x * blockDim.x;
  for (int i = blockIdx.x * blockDim.x + threadIdx.x; i < n4; i += stride) {
    float4 v = in[i];
    ushort4 r;
    r.x = f2bf(v.x); r.y = f2bf(v.y); r.z = f2bf(v.z); r.w = f2bf(v.w);
    o[i] = r;
  }
}

// ---------------- GEMM: 2-phase/K-tile, 8-MFMA clusters (unchanged from R6) --------
template <int FUSED3>
__global__ __launch_bounds__(512, 2) void gemm8(const u16* __restrict__ A0,
                                                const u16* __restrict__ Bt0,
                                                const float* __restrict__ b0,
                                                const float* __restrict__ b1,
                                                const float* __restrict__ b2,
                                                void* __restrict__ out0) {
  constexpr int K = 1024, NT = 16;
  __shared__ u16 lds[3 * 24576];

  const int y = FUSED3 ? (int)blockIdx.y : 3;
  const u16* A = A0 + (FUSED3 ? (size_t)blockIdx.y * MK : 0);
  const u16* Bt = Bt0 + (FUSED3 ? (size_t)blockIdx.y * WK : 0);
  const float* bias = FUSED3 ? (y == 0 ? b0 : y == 1 ? b1 : b2) : b0;

  const int wg = (blockIdx.x & 7) * 32 + (blockIdx.x >> 3);
  const int tm = wg >> 3, tn = wg & 7;
  const int row0 = tm << 8, col0 = tn << 7;

  const int t_ = threadIdx.x, w = t_ >> 6, l = t_ & 63;
  const int wm = w >> 1, wn = w & 1;
  const int col = l & 31, hh = l >> 5;

  f32x16 acc[2][2] = {};

  auto stA = [&](int tile, int i) {
    u16* buf = &lds[(tile % 3) * 24576];
    const int c = (w * 4 + i) * 64 + l;
    const int r = c >> 3, gl = c & 7;
    __builtin_amdgcn_global_load_lds(
        GLBP(A + (size_t)(row0 + r) * K + (tile << 6) + ((gl ^ (r & 7)) << 3)),
        LDSP(buf + (w * 4 + i) * 512), 16, 0, 0);
  };
  auto stB = [&](int tile, int i) {
    u16* buf = &lds[(tile % 3) * 24576] + 16384;
    const int c = (w * 2 + i) * 64 + l;
    const int r = c >> 3, gl = c & 7;
    __builtin_amdgcn_global_load_lds(
        GLBP(Bt + (size_t)(col0 + r) * K + (tile << 6) + ((gl ^ (r & 7)) << 3)),
        LDSP(buf + (w * 2 + i) * 512), 16, 0, 0);
  };

#pragma unroll
  for (int i = 0; i < 4; ++i) stA(0, i);
#pragma unroll
  for (int i = 0; i < 2; ++i) stB(0, i);
#pragma unroll
  for (int i = 0; i < 4; ++i) stA(1, i);
#pragma unroll
  for (int i = 0; i < 2; ++i) stB(1, i);
  asm volatile("s_waitcnt vmcnt(6)" ::: "memory");
  __builtin_amdgcn_s_barrier();

  const int ar0 = wm * 64 + col, ar1 = ar0 + 32;
  const int br0 = wn * 64 + col, br1 = br0 + 32;

#pragma unroll 1
  for (int t = 0; t < NT; ++t) {
    const u16* abuf = &lds[(t % 3) * 24576];
    const u16* bbuf = abuf + 16384;
#pragma unroll
    for (int ph = 0; ph < 2; ++ph) {
      bf16x8 a0[2], a1[2], q0[2], q1[2];
#pragma unroll
      for (int k2 = 0; k2 < 2; ++k2) {
        const int ks = ph * 2 + k2;
        a0[k2] = *(const bf16x8*)&abuf[ar0 * 64 + ((((ks << 1) + hh) ^ (ar0 & 7)) << 3)];
        a1[k2] = *(const bf16x8*)&abuf[ar1 * 64 + ((((ks << 1) + hh) ^ (ar1 & 7)) << 3)];
        q0[k2] = *(const bf16x8*)&bbuf[br0 * 64 + ((((ks << 1) + hh) ^ (br0 & 7)) << 3)];
        q1[k2] = *(const bf16x8*)&bbuf[br1 * 64 + ((((ks << 1) + hh) ^ (br1 & 7)) << 3)];
      }
      if (t + 2 < NT) {
        if (ph == 0) { stA(t + 2, 0); stA(t + 2, 1); stA(t + 2, 2); }
        else         { stA(t + 2, 3); stB(t + 2, 0); stB(t + 2, 1); }
      }
      __builtin_amdgcn_sched_barrier(0);
      __builtin_amdgcn_s_barrier();
      __builtin_amdgcn_sched_barrier(0);
      __builtin_amdgcn_s_setprio(1);
#pragma unroll
      for (int k2 = 0; k2 < 2; ++k2) {
        acc[0][0] = __builtin_amdgcn_mfma_f32_32x32x16_bf16(a0[k2], q0[k2], acc[0][0], 0, 0, 0);
        acc[0][1] = __builtin_amdgcn_mfma_f32_32x32x16_bf16(a0[k2], q1[k2], acc[0][1], 0, 0, 0);
        acc[1][0] = __builtin_amdgcn_mfma_f32_32x32x16_bf16(a1[k2], q0[k2], acc[1][0], 0, 0, 0);
        acc[1][1] = __builtin_amdgcn_mfma_f32_32x32x16_bf16(a1[k2], q1[k2], acc[1][1], 0, 0, 0);
      }
      __builtin_amdgcn_s_setprio(0);
      __builtin_amdgcn_sched_barrier(0);
    }
    if (t + 2 < NT)      asm volatile("s_waitcnt vmcnt(6)" ::: "memory");
    else if (t + 1 < NT) asm volatile("s_waitcnt vmcnt(0)" ::: "memory");
    __builtin_amdgcn_s_barrier();
  }

#pragma unroll
  for (int mi = 0; mi < 2; ++mi)
#pragma unroll
    for (int ni = 0; ni < 2; ++ni) {
      const int n = col0 + wn * 64 + ni * 32 + col;
      const float bv = bias[n];
      const int mbase = row0 + wm * 64 + mi * 32 + 4 * hh;
      if (y == 3) {
        float* O = (float*)out0;
#pragma unroll
        for (int r = 0; r < 16; ++r) {
          const int m = mbase + (r & 3) + 8 * (r >> 2);
          O[(size_t)m * Dc + n] = acc[mi][ni][r] + bv;
        }
      } else if (y == 2) {  // V: transposed + f16
        u16* Vt = (u16*)out0 + 2 * MK;
        const int h = n >> 6, dh = n & 63;
#pragma unroll
        for (int qg = 0; qg < 4; ++qg) {
          const int s0 = mbase + 8 * qg;
          const int b = s0 >> 11, s = s0 & (Sc - 1);
          f16x4v pk;
#pragma unroll
          for (int r4 = 0; r4 < 4; ++r4) pk[r4] = (_Float16)(acc[mi][ni][qg * 4 + r4] + bv);
          *(f16x4v*)&Vt[((size_t)((b * Hc + h) * DHc + dh)) * Sc + s] = pk;
        }
      } else {  // Q or K: head-split bf16, Q scaled by 1/8 * log2(e)
        u16* Oh = (u16*)out0 + (size_t)y * MK;
        const float scl = (y == 0) ? 0.125f * 1.44269504089f : 1.f;
        const int h = n >> 6, dh = n & 63;
#pragma unroll
        for (int r = 0; r < 16; ++r) {
          const int m = mbase + (r & 3) + 8 * (r >> 2);
          const int b = m >> 11, s = m & (Sc - 1);
          Oh[((size_t)((b * Hc + h) * Sc + s)) * DHc + dh] = f2bf((acc[mi][ni][r] + bv) * scl);
        }
      }
    }
}

// ---------------- Flash attention v4: K16 PV via cvt_pkrtz + permlane32_swap -------
// 4 waves, 32 q-rows/wave, KVBLK=64, double-buffered K/V (issue-early staging).
// QK: mfma_32x32x16_bf16 (S^T, swapped operands).  PV: mfma_32x32x16_f16 with the
// P fragment built in-register: per K16 chunk, lane half h holds k-offsets
// {4h+0..3, 8+4h+0..3}; B-frag needs k={8h..8h+7}.  permlane32_swap(X,Y) =
// ({X.lo,Y.lo},{X.hi,Y.hi}) gives frag words directly (HK m214v22 pattern).
__global__ __launch_bounds__(256, 4) void attn4_kernel(const u16* __restrict__ Qh,
                                                       const u16* __restrict__ Kh,
                                                       const u16* __restrict__ Vt,
                                                       u16* __restrict__ ctx) {
  __shared__ u16 smem[16384];  // 32 KB: K[2][64][64] bf16 | V^T[2][64][64] f16
  u16* K_lds = smem;
  u16* V_lds = smem + 8192;

  const int wid = (blockIdx.x & 7) * 128 + (blockIdx.x >> 3);  // XCD swizzle
  const int qt = wid & 15, bh = wid >> 4;
  const int t = threadIdx.x, w = t >> 6, l = t & 63;
  const int q = l & 31, h = l >> 5;
  const int q0 = qt * 128 + w * 32;

  bf16x8 qf[4];
  {
    const u16* qp = Qh + ((size_t)bh * Sc + q0 + q) * DHc + h * 8;
#pragma unroll
    for (int kk = 0; kk < 4; ++kk) qf[kk] = *(const bf16x8*)(qp + kk * 16);
  }

  f32x16 oacc[2] = {};
  float m_run = -3.0e38f, l_run = 0.f;

  const int lrow = l >> 3, lg = l & 7;

  auto stage = [&](int tile, int buf) {
    const int kt = tile << 6;
    u16* Kb = K_lds + buf * 4096;
    u16* Vb = V_lds + buf * 4096;
#pragma unroll
    for (int c = 0; c < 2; ++c) {
      const int rb = w * 16 + c * 8;
      const int row = rb + lrow;
      const int sg = lg ^ (row & 7);
      __builtin_amdgcn_global_load_lds(GLBP(Kh + ((size_t)bh * Sc + kt + row) * DHc + sg * 8),
                                       LDSP(&Kb[rb * 64]), 16, 0, 0);
      __builtin_amdgcn_global_load_lds(GLBP(Vt + ((size_t)bh * DHc + row) * Sc + kt + sg * 8),
                                       LDSP(&Vb[rb * 64]), 16, 0, 0);
    }
  };

  stage(0, 0);
  __syncthreads();

#pragma unroll 1
  for (int tile = 0; tile < 32; ++tile) {
    const int cur = tile & 1;
    if (tile + 1 < 32) stage(tile + 1, cur ^ 1);
    const u16* Kb = K_lds + cur * 4096;
    const u16* Vb = V_lds + cur * 4096;

    // S^T[k][q] = K · Q^T (two independent 32-row chains interleaved)
    f32x16 sacc[2] = {};
    __builtin_amdgcn_s_setprio(1);
#pragma unroll
    for (int kk = 0; kk < 4; ++kk) {
      const int kr0 = q, kr1 = 32 + q;
      bf16x8 kf0 = *(const bf16x8*)&Kb[kr0 * 64 + ((2 * kk + h) ^ (kr0 & 7)) * 8];
      bf16x8 kf1 = *(const bf16x8*)&Kb[kr1 * 64 + ((2 * kk + h) ^ (kr1 & 7)) * 8];
      sacc[0] = __builtin_amdgcn_mfma_f32_32x32x16_bf16(kf0, qf[kk], sacc[0], 0, 0, 0);
      sacc[1] = __builtin_amdgcn_mfma_f32_32x32x16_bf16(kf1, qf[kk], sacc[1], 0, 0, 0);
    }
    __builtin_amdgcn_s_setprio(0);

    // online softmax (log2 domain), defer-max (THR=8)
    float mx = sacc[0][0];
#pragma unroll
    for (int r = 1; r < 16; ++r) mx = fmaxf(mx, sacc[0][r]);
#pragma unroll
    for (int r = 0; r < 16; ++r) mx = fmaxf(mx, sacc[1][r]);
    mx = fmaxf(mx, __shfl_xor(mx, 32));
    if (__any(mx - m_run > 8.f)) {
      const float mnew = fmaxf(m_run, mx);
      const float corr = __builtin_amdgcn_exp2f(m_run - mnew);
      m_run = mnew;
      l_run *= corr;
#pragma unroll
      for (int dt = 0; dt < 2; ++dt)
#pragma unroll
        for (int r = 0; r < 16; ++r) oacc[dt][r] *= corr;
    }

    float sum = 0.f;
    // PV: per K16 chunk build P fragment in-register, 2 MFMA (dt halves)
#pragma unroll
    for (int kt32 = 0; kt32 < 2; ++kt32)
#pragma unroll
      for (int c = 0; c < 2; ++c) {
        float p0 = __builtin_amdgcn_exp2f(sacc[kt32][c * 8 + 0] - m_run);
        float p1 = __builtin_amdgcn_exp2f(sacc[kt32][c * 8 + 1] - m_run);
        float p2 = __builtin_amdgcn_exp2f(sacc[kt32][c * 8 + 2] - m_run);
        float p3 = __builtin_amdgcn_exp2f(sacc[kt32][c * 8 + 3] - m_run);
        float p4 = __builtin_amdgcn_exp2f(sacc[kt32][c * 8 + 4] - m_run);
        float p5 = __builtin_amdgcn_exp2f(sacc[kt32][c * 8 + 5] - m_run);
        float p6 = __builtin_amdgcn_exp2f(sacc[kt32][c * 8 + 6] - m_run);
        float p7 = __builtin_amdgcn_exp2f(sacc[kt32][c * 8 + 7] - m_run);
        sum += ((p0 + p1) + (p2 + p3)) + ((p4 + p5) + (p6 + p7));
        u32 X0 = __builtin_bit_cast(u32, __builtin_amdgcn_cvt_pkrtz(p0, p1));
        u32 X1 = __builtin_bit_cast(u32, __builtin_amdgcn_cvt_pkrtz(p2, p3));
        u32 Y0 = __builtin_bit_cast(u32, __builtin_amdgcn_cvt_pkrtz(p4, p5));
        u32 Y1 = __builtin_bit_cast(u32, __builtin_amdgcn_cvt_pkrtz(p6, p7));
        auto rA = __builtin_amdgcn_permlane32_swap(X0, Y0, false, false);  // {w0, w2}
        auto rB = __builtin_amdgcn_permlane32_swap(X1, Y1, false, false);  // {w1, w3}
        u32x4 wv;
        wv[0] = rA[0]; wv[1] = rB[0]; wv[2] = rA[1]; wv[3] = rB[1];
        f16x8 pf = __builtin_bit_cast(f16x8, wv);
        const int gb = kt32 * 4 + c * 2 + h;  // V granule base = k0/8 + h
        __builtin_amdgcn_s_setprio(1);
#pragma unroll
        for (int dt = 0; dt < 2; ++dt) {
          const int vrow = dt * 32 + q;
          f16x8 vf = *(const f16x8*)&Vb[vrow * 64 + ((gb ^ (vrow & 7)) * 8)];
          oacc[dt] = __builtin_amdgcn_mfma_f32_32x32x16_f16(vf, pf, oacc[dt], 0, 0, 0);
        }
        __builtin_amdgcn_s_setprio(0);
      }
    sum += __shfl_xor(sum, 32);
    l_run += sum;
    __syncthreads();
  }

  // epilogue: normalize, transpose O^T -> O through LDS, coalesced ctx write
  const float inv = 1.f / l_run;
  u16* E = smem + w * 2048;
#pragma unroll
  for (int dt = 0; dt < 2; ++dt)
#pragma unroll
    for (int rg = 0; rg < 4; ++rg) {
      bf16x4 pk;
#pragma unroll
      for (int j = 0; j < 4; ++j) pk[j] = (__bf16)(oacc[dt][rg * 4 + j] * inv);
      const int dh0 = dt * 32 + rg * 8 + 4 * h;
      int byte = q * 128 + dh0 * 2;
      byte ^= (q & 7) << 4;
      *(bf16x4*)((char*)E + byte) = pk;
    }
  __syncthreads();
  const int b = bh >> 4, head = bh & 15;
  const size_t crow = ((size_t)(b * Sc + q0 + q)) * Dc + head * 64 + h * 32;
#pragma unroll
  for (int i = 0; i < 4; ++i) {
    const int g = (4 * h + i) ^ (q & 7);
    uint4 tv = *(const uint4*)((char*)E + q * 128 + g * 16);
    *(uint4*)((u16*)ctx + crow + i * 8) = tv;
  }
}

// ---------------- launcher ----------------
extern "C" void kernel_launch(void* const* d_in, const int* in_sizes, int n_in,
                              void* d_out, int out_size, void* d_ws, size_t ws_size,
                              hipStream_t stream) {
  const float* q  = (const float*)d_in[0];
  const float* k  = (const float*)d_in[1];
  const float* v  = (const float*)d_in[2];
  const float* Wq = (const float*)d_in[3];
  const float* bq = (const float*)d_in[4];
  const float* Wk = (const float*)d_in[5];
  const float* bk = (const float*)d_in[6];
  const float* Wv = (const float*)d_in[7];
  const float* bv = (const float*)d_in[8];
  const float* Wo = (const float*)d_in[9];
  const float* bo = (const float*)d_in[10];
  float* out = (float*)d_out;

  u16* qb  = (u16*)d_ws;          // qb,kb,vb contiguous (3*MK)
  u16* Wqb = qb + 3 * MK;         // Wq,Wk,Wv,Wo contiguous (4*WK)
  u16* Qh  = Wqb + 4 * WK;        // Qh,Kh,Vt contiguous (3*MK)
  u16* Kh  = Qh + MK;
  u16* VtB = Kh + MK;
  u16* ctx = VtB + MK;

  cvt3_kernel<<<dim3(2048, 3), 256, 0, stream>>>(q, k, v, (ushort4*)qb, (int)(MK / 4));
  cvt4_kernel<<<dim3(512, 4), 256, 0, stream>>>(Wq, Wk, Wv, Wo, (ushort4*)Wqb, (int)(WK / 4));

  gemm8<1><<<dim3(256, 3), 512, 0, stream>>>(qb, Wqb, bq, bk, bv, (void*)Qh);

  attn4_kernel<<<1024, 256, 0, stream>>>(Qh, Kh, VtB, ctx);

  gemm8<0><<<dim3(256, 1), 512, 0, stream>>>(ctx, Wqb + 3 * WK, bo, bo, bo, (void*)out);
}